// Round 4
// baseline (793.347 us; speedup 1.0000x reference)
//
#include <hip/hip_runtime.h>
#include <hip/hip_fp16.h>

// ---------------------------------------------------------------------------
// MMoE extract-net, MI355X (gfx950).  R4: single fused pass over rows.
// fp16 hi/lo split (3-pass MFMA ~= fp32 accuracy), transposed formulation
// (batch = MFMA column), h1/h2 chained in registers via shfl_xor(32).
// X pre-split into fragment-ordered fp16 hi/lo planes (xsplit).
// moe: 64 rows/block, 4 waves; wave w owns experts {2w,2w+1,8+w}; wave 0
// computes gates. Gated combine in LDS fp32 accumulator (atomicAdd), one
// coalesced fp32 store. No expert-output scratch, no separate combine pass.
// ---------------------------------------------------------------------------

#define B_TOT   65536
#define IN_DIM  256
#define HD      64
#define NE      12
// ws fragment region layout, in 16-byte units:
//  A1: [e:12][rt:2][kt:16][hl:2][lane:64]   base 0      (12*4096 units)
//  A2: [e:12][rt:2][kt:4 ][hl:2][lane:64]   base 49152  (12*1024)
//  A3: same as A2                            base 61440  (12*1024)
//  AG: [kt:16][hl:2][lane:64]                base 73728  (2048)
#define U_A2 49152
#define U_A3 61440
#define U_AG 73728
#define FRAG_BYTES (75776*16)   // 1,212,416 bytes (divisible by 512)

typedef _Float16 half8  __attribute__((ext_vector_type(8)));
typedef float    f32x16 __attribute__((ext_vector_type(16)));
typedef float    f32x4  __attribute__((ext_vector_type(4)));
typedef unsigned u32x4  __attribute__((ext_vector_type(4)));

__device__ __forceinline__ unsigned short f2h(float x){
  return __builtin_bit_cast(unsigned short, (_Float16)x);
}
__device__ __forceinline__ float h2f(unsigned short u){
  return (float)__builtin_bit_cast(_Float16, u);
}
__device__ __forceinline__ void split2(float x, unsigned short& h, unsigned short& l){
  h = f2h(x); l = f2h(x - h2f(h));
}
__device__ __forceinline__ half8 FRG(u32x4 u){ return __builtin_bit_cast(half8, u); }
__device__ __forceinline__ f32x16 MF(half8 a, half8 b, f32x16 c){
  return __builtin_amdgcn_mfma_f32_32x32x16_f16(a, b, c, 0, 0, 0);
}
__device__ __forceinline__ f32x16 Z16(){
  f32x16 z;
#pragma unroll
  for (int i=0;i<16;i++) z[i]=0.f;
  return z;
}

// ---------------------------------------------------------------------------
// K0: pre-split weights into hi/lo fp16 MFMA A-fragment layout. (verified R1-R3)
// A-frag (32x32x16): lane holds row=(lane&31), k=(lane>>5)*8 + j, j=0..7.
// ---------------------------------------------------------------------------
__global__ __launch_bounds__(256) void prep(
    const float* __restrict__ Wt1, const float* __restrict__ Ws1,
    const float* __restrict__ Wt2, const float* __restrict__ Ws2,
    const float* __restrict__ Wt3, const float* __restrict__ Ws3,
    const float* __restrict__ Wg,  u32x4* __restrict__ fr){
  int id = blockIdx.x*256 + threadIdx.x;
  if (id >= 37888) return;
  int lane = id & 63;
  int kq   = lane >> 5;
  int row  = lane & 31;
  float v[8];
  unsigned ubase;
  if (id < 24576){                                   // A1 = W1^T  [h][k=in]
    int r = id >> 6; int kt = r & 15; int rt = (r>>4)&1; int e = r>>5;
    const float* W = (e<8) ? (Wt1 + (size_t)e*(IN_DIM*HD))
                           : (Ws1 + (size_t)(e-8)*(IN_DIM*HD));
    int h = rt*32 + row;
#pragma unroll
    for (int j=0;j<8;j++){ int k = kt*16 + kq*8 + j; v[j] = W[k*HD + h]; }
    ubase = (unsigned)(e*4096 + ((rt*16+kt)*2)*64 + lane);
  } else if (id < 30720){                            // A2 = W2^T  [h2][k=h1]
    int r = (id-24576) >> 6; int kt = r & 3; int rt = (r>>2)&1; int e = r>>3;
    const float* W = (e<8) ? (Wt2 + (size_t)e*(HD*HD))
                           : (Ws2 + (size_t)(e-8)*(HD*HD));
    int h = rt*32 + row;
#pragma unroll
    for (int j=0;j<8;j++){ int k = kt*16 + kq*8 + j; v[j] = W[k*HD + h]; }
    ubase = (unsigned)(U_A2 + e*1024 + ((rt*4+kt)*2)*64 + lane);
  } else if (id < 36864){                            // A3 = W3^T  [o][k=h2]
    int r = (id-30720) >> 6; int kt = r & 3; int rt = (r>>2)&1; int e = r>>3;
    const float* W = (e<8) ? (Wt3 + (size_t)e*(HD*HD))
                           : (Ws3 + (size_t)(e-8)*(HD*HD));
    int h = rt*32 + row;
#pragma unroll
    for (int j=0;j<8;j++){ int k = kt*16 + kq*8 + j; v[j] = W[k*HD + h]; }
    ubase = (unsigned)(U_A3 + e*1024 + ((rt*4+kt)*2)*64 + lane);
  } else {                                           // AG = Wg^T padded to 32 rows
    int r = (id-36864) >> 6; int kt = r;
    int g = row;
#pragma unroll
    for (int j=0;j<8;j++){
      int k = kt*16 + kq*8 + j;
      v[j] = (g < 16) ? Wg[(size_t)(g>>3)*(IN_DIM*8) + k*8 + (g&7)] : 0.f;
    }
    ubase = (unsigned)(U_AG + (kt*2)*64 + lane);
  }
  u32x4 uh, ul;
#pragma unroll
  for (int p=0;p<4;p++){
    unsigned short h0,l0,h1,l1;
    split2(v[2*p],h0,l0); split2(v[2*p+1],h1,l1);
    uh[p] = (unsigned)h0 | ((unsigned)h1<<16);
    ul[p] = (unsigned)l0 | ((unsigned)l1<<16);
  }
  fr[ubase]     = uh;
  fr[ubase+64]  = ul;
}

// ---------------------------------------------------------------------------
// K0b: split X -> fragment-ordered fp16 hi/lo planes.
// Plane layout (16B chunks): [g][ct:2][kt:16][li:32][hi:2], so a wave's
// (ct,kt) B-fragment load is one contiguous 1KB block.
// d bits: g = d>>11, ct = (d>>10)&1, kt = (d>>6)&15, li = (d>>1)&31, hi = d&1.
// ---------------------------------------------------------------------------
__global__ __launch_bounds__(256) void xsplit(
    const float* __restrict__ X, u32x4* __restrict__ xh,
    u32x4* __restrict__ xl, int n){
  int d = blockIdx.x*256 + threadIdx.x;
  if (d >= n) return;
  int hi = d&1, li = (d>>1)&31, kt = (d>>6)&15, ct = (d>>10)&1, g = d>>11;
  int row = g*64 + ct*32 + li;
  int k0  = kt*16 + hi*8;
  const float* xp = X + (size_t)row*IN_DIM + k0;
  f32x4 v0 = *(const f32x4*)xp;
  f32x4 v1 = *(const f32x4*)(xp + 4);
  float vv[8] = {v0.x,v0.y,v0.z,v0.w, v1.x,v1.y,v1.z,v1.w};
  u32x4 uh, ul;
#pragma unroll
  for (int p=0;p<4;p++){
    unsigned short h0,l0,h1,l1;
    split2(vv[2*p],h0,l0); split2(vv[2*p+1],h1,l1);
    uh[p] = (unsigned)h0 | ((unsigned)h1<<16);
    ul[p] = (unsigned)l0 | ((unsigned)l1<<16);
  }
  xh[d] = uh;
  xl[d] = ul;
}

// ---------------------------------------------------------------------------
// epilogue (layers 1/2): bias + relu + fp16 hi/lo split, packed u32 pairs.
// C/D layout: col=lane&31, row=(j&3)+8*(j>>2)+4*hi (+32*rt)  (verified)
__device__ __forceinline__ void epi12(const f32x16& A, const float* bp, int rt, int hi,
                                      unsigned* oh, unsigned* ol){
#pragma unroll
  for (int p=0;p<8;p++){
    const int j0=2*p, j1=2*p+1;
    float v0 = A[j0] + bp[rt*32 + 8*(j0>>2) + 4*hi + (j0&3)];
    float v1 = A[j1] + bp[rt*32 + 8*(j1>>2) + 4*hi + (j1&3)];
    v0 = fmaxf(v0, 0.f); v1 = fmaxf(v1, 0.f);
    unsigned short h0,l0,h1,l1;
    split2(v0,h0,l0); split2(v1,h1,l1);
    oh[p] = (unsigned)h0 | ((unsigned)h1<<16);
    ol[p] = (unsigned)l0 | ((unsigned)l1<<16);
  }
}

// Build B-frag (k=16kt+8*hi + 0..7 of h-dim) from packed C/D pairs via
// half-wave exchange. pk = 8 u32 pairs of one (rt,ct) tile; kl = kt&1. (verified)
__device__ __forceinline__ half8 bfrag(const unsigned* pk, int kl, int hi){
  unsigned p0 = pk[4*kl+0], p1 = pk[4*kl+1], p2 = pk[4*kl+2], p3 = pk[4*kl+3];
  unsigned q0 = (unsigned)__shfl_xor((int)p0, 32, 64);
  unsigned q1 = (unsigned)__shfl_xor((int)p1, 32, 64);
  unsigned q2 = (unsigned)__shfl_xor((int)p2, 32, 64);
  unsigned q3 = (unsigned)__shfl_xor((int)p3, 32, 64);
  u32x4 u;
  u.x = hi ? q2 : p0;
  u.y = hi ? q3 : p1;
  u.z = hi ? p2 : q0;
  u.w = hi ? p3 : q1;
  return FRG(u);
}

#define MM3(ACC, AH, AL, BH, BL) do { \
    ACC = MF(AH,BH,ACC); ACC = MF(AH,BL,ACC); ACC = MF(AL,BH,ACC); } while(0)

// ---------------------------------------------------------------------------
// K1: fully fused. 64 rows/block, 4 waves. Wave w: experts {2w,2w+1,8+w};
// wave 0 additionally computes gates first. Combine = LDS fp32 atomicAdd.
// ---------------------------------------------------------------------------
__global__ __launch_bounds__(256, 4) void moe(
    const char* __restrict__ xh, const char* __restrict__ xl,
    const float* __restrict__ bt1, const float* __restrict__ bs1,
    const float* __restrict__ bt2, const float* __restrict__ bs2,
    const float* __restrict__ bt3, const float* __restrict__ bs3,
    const float* __restrict__ bg,  const u32x4* __restrict__ fr,
    float* __restrict__ out){
  __shared__ float obuf[2*64*67];    // [t][o][b+pad] fp32 accumulator
  __shared__ float gbuf[64*17];      // [b][16 gates + pad]
  const int t = threadIdx.x;
  const int g = blockIdx.x;
  const int wave = t>>6, lane = t&63, li = lane&31, hi = lane>>5;
  const char* xb = xh + (size_t)g*32768;   // this block's hi plane (32KB)
  const char* lb = xl + (size_t)g*32768;   // lo plane
  const int lo = (li*2 + hi)*16;           // lane chunk offset within 1KB

  { // zero the accumulator
    f32x4 z; z.x=z.y=z.z=z.w=0.f;
    for (int u = t; u < 2144; u += 256) ((f32x4*)obuf)[u] = z;
  }

  if (wave == 0){ // ---- gates: logits^T = Wg^T(pad32) x X^T, softmax ----
    f32x16 g0 = Z16(), g1 = Z16();
    const u32x4* AG = fr + U_AG + lane;
#pragma unroll
    for (int kt=0; kt<16; ++kt){
      half8 ah  = FRG(AG[(kt*2+0)*64]);
      half8 al  = FRG(AG[(kt*2+1)*64]);
      half8 xh0 = FRG(*(const u32x4*)(xb + kt*1024 + lo));
      half8 xl0 = FRG(*(const u32x4*)(lb + kt*1024 + lo));
      half8 xh1 = FRG(*(const u32x4*)(xb + 16384 + kt*1024 + lo));
      half8 xl1 = FRG(*(const u32x4*)(lb + 16384 + kt*1024 + lo));
      MM3(g0, ah, al, xh0, xl0);
      MM3(g1, ah, al, xh1, xl1);
    }
#pragma unroll
    for (int ct=0; ct<2; ++ct){
      const f32x16& Gc = ct ? g1 : g0;
      float own[8], par[8];
#pragma unroll
      for (int j=0;j<8;j++) own[j] = Gc[j] + bg[8*(j>>2) + 4*hi + (j&3)];
#pragma unroll
      for (int j=0;j<8;j++) par[j] = __shfl_xor(own[j], 32, 64);
      float m0 = fmaxf(fmaxf(fmaxf(own[0],own[1]),fmaxf(own[2],own[3])),
                       fmaxf(fmaxf(par[0],par[1]),fmaxf(par[2],par[3])));
      float m1 = fmaxf(fmaxf(fmaxf(own[4],own[5]),fmaxf(own[6],own[7])),
                       fmaxf(fmaxf(par[4],par[5]),fmaxf(par[6],par[7])));
      float eo[8], ep[8];
#pragma unroll
      for (int j=0;j<4;j++){ eo[j] = __expf(own[j]-m0); ep[j] = __expf(par[j]-m0); }
#pragma unroll
      for (int j=4;j<8;j++){ eo[j] = __expf(own[j]-m1); ep[j] = __expf(par[j]-m1); }
      float s0 = eo[0]+eo[1]+eo[2]+eo[3]+ep[0]+ep[1]+ep[2]+ep[3];
      float s1 = eo[4]+eo[5]+eo[6]+eo[7]+ep[4]+ep[5]+ep[6]+ep[7];
      float i0 = 1.f/s0, i1 = 1.f/s1;
      if (hi == 0){   // layout: [0..3]=t0 task, [4..7]=t0 shared, [8..11]=t1 task, [12..15]=t1 shared
        float* gp = gbuf + (size_t)(ct*32+li)*17;
#pragma unroll
        for (int j=0;j<4;j++){
          gp[j]    = eo[j]*i0;   gp[4+j]  = ep[j]*i0;
          gp[8+j]  = eo[4+j]*i1; gp[12+j] = ep[4+j]*i1;
        }
      }
    }
  }
  __syncthreads();   // gates + zeroed obuf ready

#pragma unroll 1
  for (int ei=0; ei<3; ++ei){
    const int e = (ei<2) ? (wave*2+ei) : (8+wave);
    unsigned o1h[2][2][8], o1l[2][2][8];   // h1 packed [rt][ct][pair]
    { // -------- layer 1: h1^T = W1^T x X^T  (K=256)
      f32x16 a00=Z16(), a01=Z16(), a10=Z16(), a11=Z16();
      const u32x4* A1 = fr + e*4096 + lane;
#pragma unroll
      for (int kt=0; kt<16; ++kt){
        half8 ah0 = FRG(A1[( kt     *2+0)*64]);
        half8 al0 = FRG(A1[( kt     *2+1)*64]);
        half8 ah1 = FRG(A1[((16+kt) *2+0)*64]);
        half8 al1 = FRG(A1[((16+kt) *2+1)*64]);
        half8 xh0 = FRG(*(const u32x4*)(xb + kt*1024 + lo));
        half8 xl0 = FRG(*(const u32x4*)(lb + kt*1024 + lo));
        half8 xh1 = FRG(*(const u32x4*)(xb + 16384 + kt*1024 + lo));
        half8 xl1 = FRG(*(const u32x4*)(lb + 16384 + kt*1024 + lo));
        MM3(a00, ah0, al0, xh0, xl0);
        MM3(a01, ah0, al0, xh1, xl1);
        MM3(a10, ah1, al1, xh0, xl0);
        MM3(a11, ah1, al1, xh1, xl1);
      }
      const float* b1 = (e<8)? bt1+e*64 : bs1+(e-8)*64;
      epi12(a00,b1,0,hi,o1h[0][0],o1l[0][0]);
      epi12(a01,b1,0,hi,o1h[0][1],o1l[0][1]);
      epi12(a10,b1,1,hi,o1h[1][0],o1l[1][0]);
      epi12(a11,b1,1,hi,o1h[1][1],o1l[1][1]);
    }
    const float* b2 = (e<8)? bt2+e*64 : bs2+(e-8)*64;
    const float* b3 = (e<8)? bt3+e*64 : bs3+(e-8)*64;

#pragma unroll
    for (int ct=0; ct<2; ++ct){
      unsigned o2h[2][8], o2l[2][8];       // h2 packed [rt][pair], this ct
      { // -------- layer 2 (K=64, B from registers)
        f32x16 c0=Z16(), c1=Z16();
        const u32x4* A2 = fr + U_A2 + e*1024 + lane;
#pragma unroll
        for (int kt=0; kt<4; ++kt){
          half8 ah0 = FRG(A2[( kt    *2+0)*64]);
          half8 al0 = FRG(A2[( kt    *2+1)*64]);
          half8 ah1 = FRG(A2[((4+kt) *2+0)*64]);
          half8 al1 = FRG(A2[((4+kt) *2+1)*64]);
          const int rs = kt>>1, kl = kt&1;
          half8 bh = bfrag(o1h[rs][ct], kl, hi), bl = bfrag(o1l[rs][ct], kl, hi);
          MM3(c0, ah0, al0, bh, bl);
          MM3(c1, ah1, al1, bh, bl);
        }
        epi12(c0,b2,0,hi,o2h[0],o2l[0]);
        epi12(c1,b2,1,hi,o2h[1],o2l[1]);
      }
      { // -------- layer 3 (K=64) + gated LDS combine
        f32x16 d0=Z16(), d1=Z16();
        const u32x4* A3 = fr + U_A3 + e*1024 + lane;
#pragma unroll
        for (int kt=0; kt<4; ++kt){
          half8 ah0 = FRG(A3[( kt    *2+0)*64]);
          half8 al0 = FRG(A3[( kt    *2+1)*64]);
          half8 ah1 = FRG(A3[((4+kt) *2+0)*64]);
          half8 al1 = FRG(A3[((4+kt) *2+1)*64]);
          const int rs = kt>>1, kl = kt&1;
          half8 bh = bfrag(o2h[rs], kl, hi), bl = bfrag(o2l[rs], kl, hi);
          MM3(d0, ah0, al0, bh, bl);
          MM3(d1, ah1, al1, bh, bl);
        }
        auto combine = [&](const f32x16& D, int rt){
          int b = ct*32 + li;
          if (e < 8){
            float gw = gbuf[b*17 + (e>>2)*8 + (e&3)];
            float* ob = obuf + (size_t)(e>>2)*64*67 + b;
#pragma unroll
            for (int j=0;j<16;j++){
              int o = rt*32 + (j&3) + 8*(j>>2) + 4*hi;
              atomicAdd(ob + o*67, gw*(D[j]+b3[o]));
            }
          } else {
            int s = e-8;
            float g0 = gbuf[b*17 + 4 + s], g1 = gbuf[b*17 + 12 + s];
#pragma unroll
            for (int j=0;j<16;j++){
              int o = rt*32 + (j&3) + 8*(j>>2) + 4*hi;
              float v = D[j] + b3[o];
              atomicAdd(obuf + o*67 + b,        g0*v);
              atomicAdd(obuf + (64+o)*67 + b,   g1*v);
            }
          }
        };
        combine(d0, 0);
        combine(d1, 1);
      }
    }
  }
  __syncthreads();   // obuf complete

  // coalesced fp32 store: out[b][t][o]
  const size_t orow0 = (size_t)g*64;
  for (int v = t; v < 2048; v += 256){
    int b = v>>5, rest = v&31;
    int tt = rest>>4, o4 = (rest&15)*4;
    f32x4 w;
    w.x = obuf[(tt*64+o4+0)*67 + b];
    w.y = obuf[(tt*64+o4+1)*67 + b];
    w.z = obuf[(tt*64+o4+2)*67 + b];
    w.w = obuf[(tt*64+o4+3)*67 + b];
    *(f32x4*)(out + ((orow0+b)*2 + tt)*64 + o4) = w;
  }
}

// ---------------------------------------------------------------------------
extern "C" void kernel_launch(void* const* d_in, const int* in_sizes, int n_in,
                              void* d_out, int out_size, void* d_ws, size_t ws_size,
                              hipStream_t stream){
  const float* X   = (const float*)d_in[0];
  const float* Wt1 = (const float*)d_in[1];
  const float* bt1 = (const float*)d_in[2];
  const float* Wt2 = (const float*)d_in[3];
  const float* bt2 = (const float*)d_in[4];
  const float* Wt3 = (const float*)d_in[5];
  const float* bt3 = (const float*)d_in[6];
  const float* Ws1 = (const float*)d_in[7];
  const float* bs1 = (const float*)d_in[8];
  const float* Ws2 = (const float*)d_in[9];
  const float* bs2 = (const float*)d_in[10];
  const float* Ws3 = (const float*)d_in[11];
  const float* bs3 = (const float*)d_in[12];
  const float* Wg  = (const float*)d_in[13];
  const float* bg  = (const float*)d_in[14];

  char* ws = (char*)d_ws;
  u32x4* fr = (u32x4*)ws;

  // per-row ws need: xh 512 B + xl 512 B
  int C = B_TOT;
  while (C > 64 && (size_t)FRAG_BYTES + (size_t)C*1024 > ws_size) C >>= 1;
  char* xh = ws + FRAG_BYTES;
  char* xl = xh + (size_t)C*512;

  hipLaunchKernelGGL(prep, dim3(148), dim3(256), 0, stream,
                     Wt1, Ws1, Wt2, Ws2, Wt3, Ws3, Wg, fr);
  for (int r0 = 0; r0 < B_TOT; r0 += C){
    hipLaunchKernelGGL(xsplit, dim3(C/8), dim3(256), 0, stream,
                       X + (size_t)r0*IN_DIM, (u32x4*)xh, (u32x4*)xl, C*32);
    hipLaunchKernelGGL(moe, dim3(C/64), dim3(256), 0, stream,
                       xh, xl, bt1, bs1, bt2, bs2, bt3, bs3, bg, fr,
                       (float*)d_out + (size_t)r0*128);
  }
}

// Round 5
// 565.542 us; speedup vs baseline: 1.4028x; 1.4028x over previous
//
#include <hip/hip_runtime.h>
#include <hip/hip_fp16.h>

// ---------------------------------------------------------------------------
// MMoE extract-net, MI355X (gfx950).  R5: fully fused, register-sized.
// fp16 hi/lo split (3-pass MFMA ~= fp32 accuracy), transposed formulation
// (batch = MFMA column), h1/h2 chained in registers via shfl_xor(32).
// 32 rows/block, 4 waves; wave w owns experts {w, 4+w, 8+w} (t0-task, t1-task,
// shared). Every wave computes the gates for its 32 rows redundantly in
// registers (no gate wave, no gate sync). X staged once to LDS fp16 hi/lo,
// conflict-free 5-bit XOR swizzle. Combine: gated LDS fp32 atomicAdd, one
// coalesced fp32 store. Traffic ~= X(64MB) + out(32MB) + weights.
// ---------------------------------------------------------------------------

#define B_TOT   65536
#define IN_DIM  256
#define HD      64
// ws fragment region layout, in 16-byte units:
//  A1: [e:12][rt:2][kt:16][hl:2][lane:64]   base 0      (12*4096 units)
//  A2: [e:12][rt:2][kt:4 ][hl:2][lane:64]   base 49152  (12*1024)
//  A3: same as A2                            base 61440  (12*1024)
//  AG: [kt:16][hl:2][lane:64]                base 73728  (2048)
#define U_A2 49152
#define U_A3 61440
#define U_AG 73728
#define FRAG_BYTES (75776*16)   // 1,212,416 bytes

typedef _Float16 half8  __attribute__((ext_vector_type(8)));
typedef float    f32x16 __attribute__((ext_vector_type(16)));
typedef float    f32x4  __attribute__((ext_vector_type(4)));
typedef unsigned u32x4  __attribute__((ext_vector_type(4)));

__device__ __forceinline__ unsigned short f2h(float x){
  return __builtin_bit_cast(unsigned short, (_Float16)x);
}
__device__ __forceinline__ float h2f(unsigned short u){
  return (float)__builtin_bit_cast(_Float16, u);
}
__device__ __forceinline__ void split2(float x, unsigned short& h, unsigned short& l){
  h = f2h(x); l = f2h(x - h2f(h));
}
__device__ __forceinline__ half8 FRG(u32x4 u){ return __builtin_bit_cast(half8, u); }
__device__ __forceinline__ f32x16 MF(half8 a, half8 b, f32x16 c){
  return __builtin_amdgcn_mfma_f32_32x32x16_f16(a, b, c, 0, 0, 0);
}
__device__ __forceinline__ f32x16 Z16(){
  f32x16 z;
#pragma unroll
  for (int i=0;i<16;i++) z[i]=0.f;
  return z;
}
// swizzled LDS read: 8 fp16 of row `row` (0..31) at byte col offset kb.
// Full 5-bit XOR -> 32 lanes hit 32 distinct 16B slots: conflict-free b128.
__device__ __forceinline__ u32x4 lds16(const short* base, int row, int kb){
  return *(const u32x4*)((const char*)base + row*512 + (kb ^ ((row&31)<<4)));
}

// ---------------------------------------------------------------------------
// K0: pre-split weights into hi/lo fp16 MFMA A-fragment layout. (verified R1-R4)
// A-frag (32x32x16): lane holds row=(lane&31), k=(lane>>5)*8 + j, j=0..7.
// ---------------------------------------------------------------------------
__global__ __launch_bounds__(256) void prep(
    const float* __restrict__ Wt1, const float* __restrict__ Ws1,
    const float* __restrict__ Wt2, const float* __restrict__ Ws2,
    const float* __restrict__ Wt3, const float* __restrict__ Ws3,
    const float* __restrict__ Wg,  u32x4* __restrict__ fr){
  int id = blockIdx.x*256 + threadIdx.x;
  if (id >= 37888) return;
  int lane = id & 63;
  int kq   = lane >> 5;
  int row  = lane & 31;
  float v[8];
  unsigned ubase;
  if (id < 24576){                                   // A1 = W1^T  [h][k=in]
    int r = id >> 6; int kt = r & 15; int rt = (r>>4)&1; int e = r>>5;
    const float* W = (e<8) ? (Wt1 + (size_t)e*(IN_DIM*HD))
                           : (Ws1 + (size_t)(e-8)*(IN_DIM*HD));
    int h = rt*32 + row;
#pragma unroll
    for (int j=0;j<8;j++){ int k = kt*16 + kq*8 + j; v[j] = W[k*HD + h]; }
    ubase = (unsigned)(e*4096 + ((rt*16+kt)*2)*64 + lane);
  } else if (id < 30720){                            // A2 = W2^T  [h2][k=h1]
    int r = (id-24576) >> 6; int kt = r & 3; int rt = (r>>2)&1; int e = r>>3;
    const float* W = (e<8) ? (Wt2 + (size_t)e*(HD*HD))
                           : (Ws2 + (size_t)(e-8)*(HD*HD));
    int h = rt*32 + row;
#pragma unroll
    for (int j=0;j<8;j++){ int k = kt*16 + kq*8 + j; v[j] = W[k*HD + h]; }
    ubase = (unsigned)(U_A2 + e*1024 + ((rt*4+kt)*2)*64 + lane);
  } else if (id < 36864){                            // A3 = W3^T  [o][k=h2]
    int r = (id-30720) >> 6; int kt = r & 3; int rt = (r>>2)&1; int e = r>>3;
    const float* W = (e<8) ? (Wt3 + (size_t)e*(HD*HD))
                           : (Ws3 + (size_t)(e-8)*(HD*HD));
    int h = rt*32 + row;
#pragma unroll
    for (int j=0;j<8;j++){ int k = kt*16 + kq*8 + j; v[j] = W[k*HD + h]; }
    ubase = (unsigned)(U_A3 + e*1024 + ((rt*4+kt)*2)*64 + lane);
  } else {                                           // AG = Wg^T padded to 32 rows
    int r = (id-36864) >> 6; int kt = r;
    int g = row;
#pragma unroll
    for (int j=0;j<8;j++){
      int k = kt*16 + kq*8 + j;
      v[j] = (g < 16) ? Wg[(size_t)(g>>3)*(IN_DIM*8) + k*8 + (g&7)] : 0.f;
    }
    ubase = (unsigned)(U_AG + (kt*2)*64 + lane);
  }
  u32x4 uh, ul;
#pragma unroll
  for (int p=0;p<4;p++){
    unsigned short h0,l0,h1,l1;
    split2(v[2*p],h0,l0); split2(v[2*p+1],h1,l1);
    uh[p] = (unsigned)h0 | ((unsigned)h1<<16);
    ul[p] = (unsigned)l0 | ((unsigned)l1<<16);
  }
  fr[ubase]     = uh;
  fr[ubase+64]  = ul;
}

// ---------------------------------------------------------------------------
// epilogue (layers 1/2): bias + relu + fp16 hi/lo split, packed u32 pairs.
// C/D layout: col=lane&31, row=(j&3)+8*(j>>2)+4*hi (+32*rt)  (verified)
__device__ __forceinline__ void epi12(const f32x16& A, const float* bp, int rt, int hi,
                                      unsigned* oh, unsigned* ol){
#pragma unroll
  for (int p=0;p<8;p++){
    const int j0=2*p, j1=2*p+1;
    float v0 = A[j0] + bp[rt*32 + 8*(j0>>2) + 4*hi + (j0&3)];
    float v1 = A[j1] + bp[rt*32 + 8*(j1>>2) + 4*hi + (j1&3)];
    v0 = fmaxf(v0, 0.f); v1 = fmaxf(v1, 0.f);
    unsigned short h0,l0,h1,l1;
    split2(v0,h0,l0); split2(v1,h1,l1);
    oh[p] = (unsigned)h0 | ((unsigned)h1<<16);
    ol[p] = (unsigned)l0 | ((unsigned)l1<<16);
  }
}

// Build B-frag (k=16*kl+8*hi + 0..7 of h-dim within a 32-row tile) from packed
// C/D pairs via half-wave exchange. (verified R1-R4)
__device__ __forceinline__ half8 bfrag(const unsigned* pk, int kl, int hi){
  unsigned p0 = pk[4*kl+0], p1 = pk[4*kl+1], p2 = pk[4*kl+2], p3 = pk[4*kl+3];
  unsigned q0 = (unsigned)__shfl_xor((int)p0, 32, 64);
  unsigned q1 = (unsigned)__shfl_xor((int)p1, 32, 64);
  unsigned q2 = (unsigned)__shfl_xor((int)p2, 32, 64);
  unsigned q3 = (unsigned)__shfl_xor((int)p3, 32, 64);
  u32x4 u;
  u.x = hi ? q2 : p0;
  u.y = hi ? q3 : p1;
  u.z = hi ? p2 : q0;
  u.w = hi ? p3 : q1;
  return FRG(u);
}

#define MM3(ACC, AH, AL, BH, BL) do { \
    ACC = MF(AH,BH,ACC); ACC = MF(AH,BL,ACC); ACC = MF(AL,BH,ACC); } while(0)

// ---------------------------------------------------------------------------
// One expert 3-layer chain + gated LDS combine.
// TSEL: 0 = task-0 expert (gate g0 -> t0), 1 = task-1 expert (g0 -> t1),
//       2 = shared expert (g0 -> t0, g1 -> t1).
// ---------------------------------------------------------------------------
template<int TSEL>
__device__ __forceinline__ void expert_chain(
    int e, const u32x4* __restrict__ fr,
    const short* Xh, const short* Xl,
    const float* b1, const float* b2, const float* b3,
    float g0, float g1, float* obuf, int lane, int li, int hi){
  // -------- layer 1: h1^T = W1^T x X^T  (K=256)
  f32x16 a0=Z16(), a1=Z16();
  const u32x4* A1 = fr + e*4096 + lane;
#pragma unroll
  for (int kt=0; kt<16; ++kt){
    half8 ah0 = FRG(A1[( kt     *2+0)*64]);
    half8 al0 = FRG(A1[( kt     *2+1)*64]);
    half8 ah1 = FRG(A1[((16+kt) *2+0)*64]);
    half8 al1 = FRG(A1[((16+kt) *2+1)*64]);
    int kb = kt*32 + hi*16;
    half8 xh = FRG(lds16(Xh, li, kb));
    half8 xl = FRG(lds16(Xl, li, kb));
    MM3(a0, ah0, al0, xh, xl);
    MM3(a1, ah1, al1, xh, xl);
  }
  unsigned o1h[2][8], o1l[2][8];
  epi12(a0,b1,0,hi,o1h[0],o1l[0]);
  epi12(a1,b1,1,hi,o1h[1],o1l[1]);
  // -------- layer 2: h2^T = W2^T x h1^T  (K=64, B from registers)
  f32x16 c0=Z16(), c1=Z16();
  const u32x4* A2 = fr + U_A2 + e*1024 + lane;
#pragma unroll
  for (int kt=0; kt<4; ++kt){
    half8 ah0 = FRG(A2[( kt    *2+0)*64]);
    half8 al0 = FRG(A2[( kt    *2+1)*64]);
    half8 ah1 = FRG(A2[((4+kt) *2+0)*64]);
    half8 al1 = FRG(A2[((4+kt) *2+1)*64]);
    const int rs = kt>>1, kl = kt&1;
    half8 bh = bfrag(o1h[rs], kl, hi), bl = bfrag(o1l[rs], kl, hi);
    MM3(c0, ah0, al0, bh, bl);
    MM3(c1, ah1, al1, bh, bl);
  }
  unsigned o2h[2][8], o2l[2][8];
  epi12(c0,b2,0,hi,o2h[0],o2l[0]);
  epi12(c1,b2,1,hi,o2h[1],o2l[1]);
  // -------- layer 3: o^T = W3^T x h2^T  (K=64)
  f32x16 d0=Z16(), d1=Z16();
  const u32x4* A3 = fr + U_A3 + e*1024 + lane;
#pragma unroll
  for (int kt=0; kt<4; ++kt){
    half8 ah0 = FRG(A3[( kt    *2+0)*64]);
    half8 al0 = FRG(A3[( kt    *2+1)*64]);
    half8 ah1 = FRG(A3[((4+kt) *2+0)*64]);
    half8 al1 = FRG(A3[((4+kt) *2+1)*64]);
    const int rs = kt>>1, kl = kt&1;
    half8 bh = bfrag(o2h[rs], kl, hi), bl = bfrag(o2l[rs], kl, hi);
    MM3(d0, ah0, al0, bh, bl);
    MM3(d1, ah1, al1, bh, bl);
  }
  // -------- gated combine into LDS accumulator obuf[t][o][b(+pad)]
#pragma unroll
  for (int rt=0; rt<2; ++rt){
    const f32x16& D = rt ? d1 : d0;
#pragma unroll
    for (int j=0;j<16;j++){
      int o = rt*32 + (j&3) + 8*(j>>2) + 4*hi;
      float v = D[j] + b3[o];
      if (TSEL == 0){
        atomicAdd(&obuf[(o)*33 + li], g0*v);
      } else if (TSEL == 1){
        atomicAdd(&obuf[(64+o)*33 + li], g0*v);
      } else {
        atomicAdd(&obuf[(o)*33 + li],    g0*v);
        atomicAdd(&obuf[(64+o)*33 + li], g1*v);
      }
    }
  }
}

// ---------------------------------------------------------------------------
// K1: fully fused. 32 rows/block, 4 waves; wave w -> experts {w, 4+w, 8+w}.
// ---------------------------------------------------------------------------
__global__ __launch_bounds__(256, 3) void moe(
    const float* __restrict__ X,
    const float* __restrict__ bt1, const float* __restrict__ bs1,
    const float* __restrict__ bt2, const float* __restrict__ bs2,
    const float* __restrict__ bt3, const float* __restrict__ bs3,
    const float* __restrict__ bg,  const u32x4* __restrict__ fr,
    float* __restrict__ out){
  __shared__ __align__(16) short Xh[32*256];   // 16 KiB fp16 hi plane
  __shared__ __align__(16) short Xl[32*256];   // 16 KiB fp16 lo plane
  __shared__ float obuf[2*64*33];              // 16.9 KiB fp32 accumulator
  const int t = threadIdx.x;
  const int grow0 = blockIdx.x*32;

  { // stage X -> hi/lo fp16 LDS, 5-bit XOR swizzle (conflict-free reads)
#pragma unroll
    for (int s=0; s<4; ++s){
      int u = t + s*256;                 // 1024 units of 8 values
      int r = u>>5, c8 = u&31;
      const float* xp = X + (size_t)(grow0 + r)*IN_DIM + c8*8;
      f32x4 v0 = *(const f32x4*)xp;
      f32x4 v1 = *(const f32x4*)(xp + 4);
      float vv[8] = {v0.x,v0.y,v0.z,v0.w, v1.x,v1.y,v1.z,v1.w};
      u32x4 uh, ul;
#pragma unroll
      for (int p=0;p<4;p++){
        unsigned short h0,l0,h1,l1;
        split2(vv[2*p],h0,l0); split2(vv[2*p+1],h1,l1);
        uh[p] = (unsigned)h0 | ((unsigned)h1<<16);
        ul[p] = (unsigned)l0 | ((unsigned)l1<<16);
      }
      int addr = r*512 + ((c8*16) ^ ((r&31)<<4));
      *(u32x4*)((char*)Xh + addr) = uh;
      *(u32x4*)((char*)Xl + addr) = ul;
    }
  }
  // zero the output accumulator
  for (int u = t; u < 2*64*33; u += 256) obuf[u] = 0.f;
  __syncthreads();   // X planes + zeroed obuf ready

  const int wave = t>>6, lane = t&63, li = lane&31, hi = lane>>5;

  // ---- gates (every wave, in registers; only this wave's 4 scalars kept)
  float gt0, gt1, gs0, gs1;
  {
    f32x16 gl = Z16();
    const u32x4* AG = fr + U_AG + lane;
#pragma unroll
    for (int kt=0; kt<16; ++kt){
      half8 ah = FRG(AG[(kt*2+0)*64]);
      half8 al = FRG(AG[(kt*2+1)*64]);
      int kb = kt*32 + hi*16;
      half8 xh = FRG(lds16(Xh, li, kb));
      half8 xl = FRG(lds16(Xl, li, kb));
      MM3(gl, ah, al, xh, xl);
    }
    float own[8], par[8];
#pragma unroll
    for (int j=0;j<8;j++) own[j] = gl[j] + bg[8*(j>>2) + 4*hi + (j&3)];
#pragma unroll
    for (int j=0;j<8;j++) par[j] = __shfl_xor(own[j], 32, 64);
    // t0 logits = rows 0..7, t1 logits = rows 8..15 (own/par swap by hi)
    float m0 = fmaxf(fmaxf(fmaxf(own[0],own[1]),fmaxf(own[2],own[3])),
                     fmaxf(fmaxf(par[0],par[1]),fmaxf(par[2],par[3])));
    float m1 = fmaxf(fmaxf(fmaxf(own[4],own[5]),fmaxf(own[6],own[7])),
                     fmaxf(fmaxf(par[4],par[5]),fmaxf(par[6],par[7])));
    float eo[8], ep[8];
#pragma unroll
    for (int j=0;j<4;j++){ eo[j] = __expf(own[j]-m0); ep[j] = __expf(par[j]-m0); }
#pragma unroll
    for (int j=4;j<8;j++){ eo[j] = __expf(own[j]-m1); ep[j] = __expf(par[j]-m1); }
    float s0 = eo[0]+eo[1]+eo[2]+eo[3]+ep[0]+ep[1]+ep[2]+ep[3];
    float s1 = eo[4]+eo[5]+eo[6]+eo[7]+ep[4]+ep[5]+ep[6]+ep[7];
    float i0 = 1.f/s0, i1 = 1.f/s1;
    // rows 0-3 = t0 task gates, 4-7 = t0 shared, 8-11 = t1 task, 12-15 = t1 shared
    // hi=0: own = rows{0-3,8-11}, par = rows{4-7,12-15}; hi=1 swapped.
    if      (wave==0){ gt0=(hi?ep[0]:eo[0])*i0; gs0=(hi?eo[0]:ep[0])*i0;
                       gt1=(hi?ep[4]:eo[4])*i1; gs1=(hi?eo[4]:ep[4])*i1; }
    else if (wave==1){ gt0=(hi?ep[1]:eo[1])*i0; gs0=(hi?eo[1]:ep[1])*i0;
                       gt1=(hi?ep[5]:eo[5])*i1; gs1=(hi?eo[5]:ep[5])*i1; }
    else if (wave==2){ gt0=(hi?ep[2]:eo[2])*i0; gs0=(hi?eo[2]:ep[2])*i0;
                       gt1=(hi?ep[6]:eo[6])*i1; gs1=(hi?eo[6]:ep[6])*i1; }
    else             { gt0=(hi?ep[3]:eo[3])*i0; gs0=(hi?eo[3]:ep[3])*i0;
                       gt1=(hi?ep[7]:eo[7])*i1; gs1=(hi?eo[7]:ep[7])*i1; }
  }

  // ---- experts: {w (t0 task), 4+w (t1 task), 8+w (shared)}
  expert_chain<0>(wave,   fr, Xh, Xl, bt1+wave*64,     bt2+wave*64,     bt3+wave*64,
                  gt0, 0.f, obuf, lane, li, hi);
  expert_chain<1>(4+wave, fr, Xh, Xl, bt1+(4+wave)*64, bt2+(4+wave)*64, bt3+(4+wave)*64,
                  gt1, 0.f, obuf, lane, li, hi);
  expert_chain<2>(8+wave, fr, Xh, Xl, bs1+wave*64,     bs2+wave*64,     bs3+wave*64,
                  gs0, gs1, obuf, lane, li, hi);

  __syncthreads();   // obuf complete

  // coalesced fp32 store: out[b][t][o], 4096 floats
#pragma unroll
  for (int s=0; s<4; ++s){
    int u = t + s*256;
    int idx = u*4;
    int b = idx>>7, tt = (idx>>6)&1, o = idx&63;
    f32x4 w;
    w.x = obuf[(tt*64+o+0)*33 + b];
    w.y = obuf[(tt*64+o+1)*33 + b];
    w.z = obuf[(tt*64+o+2)*33 + b];
    w.w = obuf[(tt*64+o+3)*33 + b];
    *(f32x4*)(out + (size_t)(grow0+b)*128 + tt*64 + o) = w;
  }
}

// ---------------------------------------------------------------------------
extern "C" void kernel_launch(void* const* d_in, const int* in_sizes, int n_in,
                              void* d_out, int out_size, void* d_ws, size_t ws_size,
                              hipStream_t stream){
  const float* X   = (const float*)d_in[0];
  const float* Wt1 = (const float*)d_in[1];
  const float* bt1 = (const float*)d_in[2];
  const float* Wt2 = (const float*)d_in[3];
  const float* bt2 = (const float*)d_in[4];
  const float* Wt3 = (const float*)d_in[5];
  const float* bt3 = (const float*)d_in[6];
  const float* Ws1 = (const float*)d_in[7];
  const float* bs1 = (const float*)d_in[8];
  const float* Ws2 = (const float*)d_in[9];
  const float* bs2 = (const float*)d_in[10];
  const float* Ws3 = (const float*)d_in[11];
  const float* bs3 = (const float*)d_in[12];
  const float* Wg  = (const float*)d_in[13];
  const float* bg  = (const float*)d_in[14];

  u32x4* fr = (u32x4*)d_ws;

  hipLaunchKernelGGL(prep, dim3(148), dim3(256), 0, stream,
                     Wt1, Ws1, Wt2, Ws2, Wt3, Ws3, Wg, fr);
  hipLaunchKernelGGL(moe, dim3(B_TOT/32), dim3(256), 0, stream,
                     X, bt1, bs1, bt2, bs2, bt3, bs3, bg, fr, (float*)d_out);
}

// Round 6
// 522.917 us; speedup vs baseline: 1.5172x; 1.0815x over previous
//
#include <hip/hip_runtime.h>
#include <hip/hip_fp16.h>

// ---------------------------------------------------------------------------
// MMoE extract-net, MI355X (gfx950).  R6: fused 32-row blocks (R5 shell) with
// ILP restored: task-expert PAIR interleaved in layer1 (4 accs), gate GEMM
// interleaved with shared-expert layer1 (3 accs). In-LDS gated combine.
// fp16 hi/lo split (3-pass MFMA ~= fp32 accuracy), transposed formulation
// (batch = MFMA column), h1/h2 chained in registers via shfl_xor(32).
// ---------------------------------------------------------------------------

#define B_TOT   65536
#define IN_DIM  256
#define HD      64
// ws fragment region layout, in 16-byte units:
//  A1: [e:12][rt:2][kt:16][hl:2][lane:64]   base 0      (12*4096 units)
//  A2: [e:12][rt:2][kt:4 ][hl:2][lane:64]   base 49152  (12*1024)
//  A3: same as A2                            base 61440  (12*1024)
//  AG: [kt:16][hl:2][lane:64]                base 73728  (2048)
#define U_A2 49152
#define U_A3 61440
#define U_AG 73728
#define FRAG_BYTES (75776*16)   // 1,212,416 bytes

typedef _Float16 half8  __attribute__((ext_vector_type(8)));
typedef float    f32x16 __attribute__((ext_vector_type(16)));
typedef float    f32x4  __attribute__((ext_vector_type(4)));
typedef unsigned u32x4  __attribute__((ext_vector_type(4)));

__device__ __forceinline__ unsigned short f2h(float x){
  return __builtin_bit_cast(unsigned short, (_Float16)x);
}
__device__ __forceinline__ float h2f(unsigned short u){
  return (float)__builtin_bit_cast(_Float16, u);
}
__device__ __forceinline__ void split2(float x, unsigned short& h, unsigned short& l){
  h = f2h(x); l = f2h(x - h2f(h));
}
__device__ __forceinline__ half8 FRG(u32x4 u){ return __builtin_bit_cast(half8, u); }
__device__ __forceinline__ f32x16 MF(half8 a, half8 b, f32x16 c){
  return __builtin_amdgcn_mfma_f32_32x32x16_f16(a, b, c, 0, 0, 0);
}
__device__ __forceinline__ f32x16 Z16(){
  f32x16 z;
#pragma unroll
  for (int i=0;i<16;i++) z[i]=0.f;
  return z;
}
// swizzled LDS read: 8 fp16 of row `row` (0..31) at byte col offset kb.
// Full 5-bit XOR -> 32 lanes hit 32 distinct 16B slots: conflict-free b128.
__device__ __forceinline__ u32x4 lds16(const short* base, int row, int kb){
  return *(const u32x4*)((const char*)base + row*512 + (kb ^ ((row&31)<<4)));
}

// ---------------------------------------------------------------------------
// K0: pre-split weights into hi/lo fp16 MFMA A-fragment layout. (verified R1-R5)
// A-frag (32x32x16): lane holds row=(lane&31), k=(lane>>5)*8 + j, j=0..7.
// ---------------------------------------------------------------------------
__global__ __launch_bounds__(256) void prep(
    const float* __restrict__ Wt1, const float* __restrict__ Ws1,
    const float* __restrict__ Wt2, const float* __restrict__ Ws2,
    const float* __restrict__ Wt3, const float* __restrict__ Ws3,
    const float* __restrict__ Wg,  u32x4* __restrict__ fr){
  int id = blockIdx.x*256 + threadIdx.x;
  if (id >= 37888) return;
  int lane = id & 63;
  int kq   = lane >> 5;
  int row  = lane & 31;
  float v[8];
  unsigned ubase;
  if (id < 24576){                                   // A1 = W1^T  [h][k=in]
    int r = id >> 6; int kt = r & 15; int rt = (r>>4)&1; int e = r>>5;
    const float* W = (e<8) ? (Wt1 + (size_t)e*(IN_DIM*HD))
                           : (Ws1 + (size_t)(e-8)*(IN_DIM*HD));
    int h = rt*32 + row;
#pragma unroll
    for (int j=0;j<8;j++){ int k = kt*16 + kq*8 + j; v[j] = W[k*HD + h]; }
    ubase = (unsigned)(e*4096 + ((rt*16+kt)*2)*64 + lane);
  } else if (id < 30720){                            // A2 = W2^T  [h2][k=h1]
    int r = (id-24576) >> 6; int kt = r & 3; int rt = (r>>2)&1; int e = r>>3;
    const float* W = (e<8) ? (Wt2 + (size_t)e*(HD*HD))
                           : (Ws2 + (size_t)(e-8)*(HD*HD));
    int h = rt*32 + row;
#pragma unroll
    for (int j=0;j<8;j++){ int k = kt*16 + kq*8 + j; v[j] = W[k*HD + h]; }
    ubase = (unsigned)(U_A2 + e*1024 + ((rt*4+kt)*2)*64 + lane);
  } else if (id < 36864){                            // A3 = W3^T  [o][k=h2]
    int r = (id-30720) >> 6; int kt = r & 3; int rt = (r>>2)&1; int e = r>>3;
    const float* W = (e<8) ? (Wt3 + (size_t)e*(HD*HD))
                           : (Ws3 + (size_t)(e-8)*(HD*HD));
    int h = rt*32 + row;
#pragma unroll
    for (int j=0;j<8;j++){ int k = kt*16 + kq*8 + j; v[j] = W[k*HD + h]; }
    ubase = (unsigned)(U_A3 + e*1024 + ((rt*4+kt)*2)*64 + lane);
  } else {                                           // AG = Wg^T padded to 32 rows
    int r = (id-36864) >> 6; int kt = r;
    int g = row;
#pragma unroll
    for (int j=0;j<8;j++){
      int k = kt*16 + kq*8 + j;
      v[j] = (g < 16) ? Wg[(size_t)(g>>3)*(IN_DIM*8) + k*8 + (g&7)] : 0.f;
    }
    ubase = (unsigned)(U_AG + (kt*2)*64 + lane);
  }
  u32x4 uh, ul;
#pragma unroll
  for (int p=0;p<4;p++){
    unsigned short h0,l0,h1,l1;
    split2(v[2*p],h0,l0); split2(v[2*p+1],h1,l1);
    uh[p] = (unsigned)h0 | ((unsigned)h1<<16);
    ul[p] = (unsigned)l0 | ((unsigned)l1<<16);
  }
  fr[ubase]     = uh;
  fr[ubase+64]  = ul;
}

// ---------------------------------------------------------------------------
// epilogue (layers 1/2): bias + relu + fp16 hi/lo split, packed u32 pairs.
// C/D layout: col=lane&31, row=(j&3)+8*(j>>2)+4*hi (+32*rt)  (verified)
__device__ __forceinline__ void epi12(const f32x16& A, const float* bp, int rt, int hi,
                                      unsigned* oh, unsigned* ol){
#pragma unroll
  for (int p=0;p<8;p++){
    const int j0=2*p, j1=2*p+1;
    float v0 = A[j0] + bp[rt*32 + 8*(j0>>2) + 4*hi + (j0&3)];
    float v1 = A[j1] + bp[rt*32 + 8*(j1>>2) + 4*hi + (j1&3)];
    v0 = fmaxf(v0, 0.f); v1 = fmaxf(v1, 0.f);
    unsigned short h0,l0,h1,l1;
    split2(v0,h0,l0); split2(v1,h1,l1);
    oh[p] = (unsigned)h0 | ((unsigned)h1<<16);
    ol[p] = (unsigned)l0 | ((unsigned)l1<<16);
  }
}

// Build B-frag (k=16*kl+8*hi + 0..7 of h-dim within a 32-row tile) from packed
// C/D pairs via half-wave exchange. (verified R1-R5)
__device__ __forceinline__ half8 bfrag(const unsigned* pk, int kl, int hi){
  unsigned p0 = pk[4*kl+0], p1 = pk[4*kl+1], p2 = pk[4*kl+2], p3 = pk[4*kl+3];
  unsigned q0 = (unsigned)__shfl_xor((int)p0, 32, 64);
  unsigned q1 = (unsigned)__shfl_xor((int)p1, 32, 64);
  unsigned q2 = (unsigned)__shfl_xor((int)p2, 32, 64);
  unsigned q3 = (unsigned)__shfl_xor((int)p3, 32, 64);
  u32x4 u;
  u.x = hi ? q2 : p0;
  u.y = hi ? q3 : p1;
  u.z = hi ? p2 : q0;
  u.w = hi ? p3 : q1;
  return FRG(u);
}

#define MM3(ACC, AH, AL, BH, BL) do { \
    ACC = MF(AH,BH,ACC); ACC = MF(AH,BL,ACC); ACC = MF(AL,BH,ACC); } while(0)

// ---------------------------------------------------------------------------
// Layers 2+3 + gated LDS combine for one expert, given packed h1.
// TSEL: 0 = task-0 expert (g0 -> t0), 1 = task-1 expert (g0 -> t1),
//       2 = shared expert (g0 -> t0, g1 -> t1).            (verified R5 logic)
// ---------------------------------------------------------------------------
template<int TSEL>
__device__ __forceinline__ void expert_tail(
    int e, const u32x4* __restrict__ fr,
    const float* b2, const float* b3,
    const unsigned o1h[2][8], const unsigned o1l[2][8],
    float g0, float g1, float* obuf, int lane, int li, int hi){
  // -------- layer 2: h2^T = W2^T x h1^T  (K=64, B from registers)
  f32x16 c0=Z16(), c1=Z16();
  const u32x4* A2 = fr + U_A2 + e*1024 + lane;
#pragma unroll
  for (int kt=0; kt<4; ++kt){
    half8 ah0 = FRG(A2[( kt    *2+0)*64]);
    half8 al0 = FRG(A2[( kt    *2+1)*64]);
    half8 ah1 = FRG(A2[((4+kt) *2+0)*64]);
    half8 al1 = FRG(A2[((4+kt) *2+1)*64]);
    const int rs = kt>>1, kl = kt&1;
    half8 bh = bfrag(o1h[rs], kl, hi), bl = bfrag(o1l[rs], kl, hi);
    MM3(c0, ah0, al0, bh, bl);
    MM3(c1, ah1, al1, bh, bl);
  }
  unsigned o2h[2][8], o2l[2][8];
  epi12(c0,b2,0,hi,o2h[0],o2l[0]);
  epi12(c1,b2,1,hi,o2h[1],o2l[1]);
  // -------- layer 3: o^T = W3^T x h2^T  (K=64)
  f32x16 d0=Z16(), d1=Z16();
  const u32x4* A3 = fr + U_A3 + e*1024 + lane;
#pragma unroll
  for (int kt=0; kt<4; ++kt){
    half8 ah0 = FRG(A3[( kt    *2+0)*64]);
    half8 al0 = FRG(A3[( kt    *2+1)*64]);
    half8 ah1 = FRG(A3[((4+kt) *2+0)*64]);
    half8 al1 = FRG(A3[((4+kt) *2+1)*64]);
    const int rs = kt>>1, kl = kt&1;
    half8 bh = bfrag(o2h[rs], kl, hi), bl = bfrag(o2l[rs], kl, hi);
    MM3(d0, ah0, al0, bh, bl);
    MM3(d1, ah1, al1, bh, bl);
  }
  // -------- gated combine into LDS accumulator obuf[t][o][b(+pad)]
#pragma unroll
  for (int rt=0; rt<2; ++rt){
    const f32x16& D = rt ? d1 : d0;
#pragma unroll
    for (int j=0;j<16;j++){
      int o = rt*32 + (j&3) + 8*(j>>2) + 4*hi;
      float v = D[j] + b3[o];
      if (TSEL == 0){
        atomicAdd(&obuf[(o)*33 + li], g0*v);
      } else if (TSEL == 1){
        atomicAdd(&obuf[(64+o)*33 + li], g0*v);
      } else {
        atomicAdd(&obuf[(o)*33 + li],    g0*v);
        atomicAdd(&obuf[(64+o)*33 + li], g1*v);
      }
    }
  }
}

// ---------------------------------------------------------------------------
// K1: fully fused. 32 rows/block, 4 waves; wave w -> experts {w, 4+w, 8+w}.
// Order per wave: [shared L1 + gate GEMM interleaved] -> softmax -> shared
// tail -> [task pair L1 interleaved] -> task tails.
// ---------------------------------------------------------------------------
__global__ __launch_bounds__(256, 3) void moe(
    const float* __restrict__ X,
    const float* __restrict__ bt1, const float* __restrict__ bs1,
    const float* __restrict__ bt2, const float* __restrict__ bs2,
    const float* __restrict__ bt3, const float* __restrict__ bs3,
    const float* __restrict__ bg,  const u32x4* __restrict__ fr,
    float* __restrict__ out){
  __shared__ __align__(16) short Xh[32*256];   // 16 KiB fp16 hi plane
  __shared__ __align__(16) short Xl[32*256];   // 16 KiB fp16 lo plane
  __shared__ float obuf[2*64*33];              // 16.9 KiB fp32 accumulator
  const int t = threadIdx.x;
  const int grow0 = blockIdx.x*32;

  { // stage X -> hi/lo fp16 LDS, 5-bit XOR swizzle (conflict-free reads)
#pragma unroll
    for (int s=0; s<4; ++s){
      int u = t + s*256;                 // 1024 units of 8 values
      int r = u>>5, c8 = u&31;
      const float* xp = X + (size_t)(grow0 + r)*IN_DIM + c8*8;
      f32x4 v0 = *(const f32x4*)xp;
      f32x4 v1 = *(const f32x4*)(xp + 4);
      float vv[8] = {v0.x,v0.y,v0.z,v0.w, v1.x,v1.y,v1.z,v1.w};
      u32x4 uh, ul;
#pragma unroll
      for (int p=0;p<4;p++){
        unsigned short h0,l0,h1,l1;
        split2(vv[2*p],h0,l0); split2(vv[2*p+1],h1,l1);
        uh[p] = (unsigned)h0 | ((unsigned)h1<<16);
        ul[p] = (unsigned)l0 | ((unsigned)l1<<16);
      }
      int addr = r*512 + ((c8*16) ^ ((r&31)<<4));
      *(u32x4*)((char*)Xh + addr) = uh;
      *(u32x4*)((char*)Xl + addr) = ul;
    }
  }
  // zero the output accumulator
  for (int u = t; u < 2*64*33; u += 256) obuf[u] = 0.f;
  __syncthreads();   // X planes + zeroed obuf ready

  const int wave = t>>6, lane = t&63, li = lane&31, hi = lane>>5;

  // ---- Phase A: shared-expert layer1 + gate GEMM, interleaved (3 accs)
  float gt0, gt1, gs0, gs1;                 // this wave's gate scalars
  unsigned o1h[2][8], o1l[2][8];            // packed h1 (reused per expert)
  {
    f32x16 s0=Z16(), s1=Z16(), gl=Z16();
    const u32x4* A1s = fr + (size_t)(8+wave)*4096 + lane;
    const u32x4* AG  = fr + U_AG + lane;
#pragma unroll
    for (int kt=0; kt<16; ++kt){
      half8 sh0 = FRG(A1s[( kt     *2+0)*64]);
      half8 sl0 = FRG(A1s[( kt     *2+1)*64]);
      half8 sh1 = FRG(A1s[((16+kt) *2+0)*64]);
      half8 sl1 = FRG(A1s[((16+kt) *2+1)*64]);
      half8 gh  = FRG(AG[(kt*2+0)*64]);
      half8 glo = FRG(AG[(kt*2+1)*64]);
      int kb = kt*32 + hi*16;
      half8 xh = FRG(lds16(Xh, li, kb));
      half8 xl = FRG(lds16(Xl, li, kb));
      MM3(s0, sh0, sl0, xh, xl);
      MM3(s1, sh1, sl1, xh, xl);
      MM3(gl, gh,  glo, xh, xl);
    }
    // ---- softmax on gate logits (R5-verified mapping)
    {
      float own[8], par[8];
#pragma unroll
      for (int j=0;j<8;j++) own[j] = gl[j] + bg[8*(j>>2) + 4*hi + (j&3)];
#pragma unroll
      for (int j=0;j<8;j++) par[j] = __shfl_xor(own[j], 32, 64);
      float m0 = fmaxf(fmaxf(fmaxf(own[0],own[1]),fmaxf(own[2],own[3])),
                       fmaxf(fmaxf(par[0],par[1]),fmaxf(par[2],par[3])));
      float m1 = fmaxf(fmaxf(fmaxf(own[4],own[5]),fmaxf(own[6],own[7])),
                       fmaxf(fmaxf(par[4],par[5]),fmaxf(par[6],par[7])));
      float eo[8], ep[8];
#pragma unroll
      for (int j=0;j<4;j++){ eo[j] = __expf(own[j]-m0); ep[j] = __expf(par[j]-m0); }
#pragma unroll
      for (int j=4;j<8;j++){ eo[j] = __expf(own[j]-m1); ep[j] = __expf(par[j]-m1); }
      float s0v = eo[0]+eo[1]+eo[2]+eo[3]+ep[0]+ep[1]+ep[2]+ep[3];
      float s1v = eo[4]+eo[5]+eo[6]+eo[7]+ep[4]+ep[5]+ep[6]+ep[7];
      float i0 = 1.f/s0v, i1 = 1.f/s1v;
      if      (wave==0){ gt0=(hi?ep[0]:eo[0])*i0; gs0=(hi?eo[0]:ep[0])*i0;
                         gt1=(hi?ep[4]:eo[4])*i1; gs1=(hi?eo[4]:ep[4])*i1; }
      else if (wave==1){ gt0=(hi?ep[1]:eo[1])*i0; gs0=(hi?eo[1]:ep[1])*i0;
                         gt1=(hi?ep[5]:eo[5])*i1; gs1=(hi?eo[5]:ep[5])*i1; }
      else if (wave==2){ gt0=(hi?ep[2]:eo[2])*i0; gs0=(hi?eo[2]:ep[2])*i0;
                         gt1=(hi?ep[6]:eo[6])*i1; gs1=(hi?eo[6]:ep[6])*i1; }
      else             { gt0=(hi?ep[3]:eo[3])*i0; gs0=(hi?eo[3]:ep[3])*i0;
                         gt1=(hi?ep[7]:eo[7])*i1; gs1=(hi?eo[7]:ep[7])*i1; }
    }
    epi12(s0, bs1+wave*64, 0, hi, o1h[0], o1l[0]);
    epi12(s1, bs1+wave*64, 1, hi, o1h[1], o1l[1]);
    expert_tail<2>(8+wave, fr, bs2+wave*64, bs3+wave*64,
                   o1h, o1l, gs0, gs1, obuf, lane, li, hi);
  }

  // ---- Phase B: task-expert pair layer1, interleaved (4 accs)
  unsigned o1hB[2][8], o1lB[2][8];
  {
    f32x16 a0=Z16(), a1=Z16(), a2=Z16(), a3=Z16();
    const u32x4* A1a = fr + (size_t)wave*4096 + lane;
    const u32x4* A1b = fr + (size_t)(4+wave)*4096 + lane;
#pragma unroll
    for (int kt=0; kt<16; ++kt){
      half8 ah0 = FRG(A1a[( kt     *2+0)*64]);
      half8 al0 = FRG(A1a[( kt     *2+1)*64]);
      half8 ah1 = FRG(A1a[((16+kt) *2+0)*64]);
      half8 al1 = FRG(A1a[((16+kt) *2+1)*64]);
      half8 bh0 = FRG(A1b[( kt     *2+0)*64]);
      half8 bl0 = FRG(A1b[( kt     *2+1)*64]);
      half8 bh1 = FRG(A1b[((16+kt) *2+0)*64]);
      half8 bl1 = FRG(A1b[((16+kt) *2+1)*64]);
      int kb = kt*32 + hi*16;
      half8 xh = FRG(lds16(Xh, li, kb));
      half8 xl = FRG(lds16(Xl, li, kb));
      MM3(a0, ah0, al0, xh, xl);
      MM3(a1, ah1, al1, xh, xl);
      MM3(a2, bh0, bl0, xh, xl);
      MM3(a3, bh1, bl1, xh, xl);
    }
    epi12(a0, bt1+wave*64,     0, hi, o1h[0],  o1l[0]);
    epi12(a1, bt1+wave*64,     1, hi, o1h[1],  o1l[1]);
    epi12(a2, bt1+(4+wave)*64, 0, hi, o1hB[0], o1lB[0]);
    epi12(a3, bt1+(4+wave)*64, 1, hi, o1hB[1], o1lB[1]);
  }
  expert_tail<0>(wave,   fr, bt2+wave*64,     bt3+wave*64,
                 o1h,  o1l,  gt0, 0.f, obuf, lane, li, hi);
  expert_tail<1>(4+wave, fr, bt2+(4+wave)*64, bt3+(4+wave)*64,
                 o1hB, o1lB, gt1, 0.f, obuf, lane, li, hi);

  __syncthreads();   // obuf complete

  // coalesced fp32 store: out[b][t][o], 4096 floats
#pragma unroll
  for (int s=0; s<4; ++s){
    int u = t + s*256;
    int idx = u*4;
    int b = idx>>7, tt = (idx>>6)&1, o = idx&63;
    f32x4 w;
    w.x = obuf[(tt*64+o+0)*33 + b];
    w.y = obuf[(tt*64+o+1)*33 + b];
    w.z = obuf[(tt*64+o+2)*33 + b];
    w.w = obuf[(tt*64+o+3)*33 + b];
    *(f32x4*)(out + (size_t)(grow0+b)*128 + tt*64 + o) = w;
  }
}

// ---------------------------------------------------------------------------
extern "C" void kernel_launch(void* const* d_in, const int* in_sizes, int n_in,
                              void* d_out, int out_size, void* d_ws, size_t ws_size,
                              hipStream_t stream){
  const float* X   = (const float*)d_in[0];
  const float* Wt1 = (const float*)d_in[1];
  const float* bt1 = (const float*)d_in[2];
  const float* Wt2 = (const float*)d_in[3];
  const float* bt2 = (const float*)d_in[4];
  const float* Wt3 = (const float*)d_in[5];
  const float* bt3 = (const float*)d_in[6];
  const float* Ws1 = (const float*)d_in[7];
  const float* bs1 = (const float*)d_in[8];
  const float* Ws2 = (const float*)d_in[9];
  const float* bs2 = (const float*)d_in[10];
  const float* Ws3 = (const float*)d_in[11];
  const float* bs3 = (const float*)d_in[12];
  const float* Wg  = (const float*)d_in[13];
  const float* bg  = (const float*)d_in[14];

  u32x4* fr = (u32x4*)d_ws;

  hipLaunchKernelGGL(prep, dim3(148), dim3(256), 0, stream,
                     Wt1, Ws1, Wt2, Ws2, Wt3, Ws3, Wg, fr);
  hipLaunchKernelGGL(moe, dim3(B_TOT/32), dim3(256), 0, stream,
                     X, bt1, bs1, bt2, bs2, bt3, bs3, bg, fr, (float*)d_out);
}